// Round 1
// baseline (222.533 us; speedup 1.0000x reference)
//
#include <hip/hip_runtime.h>
#include <hip/hip_bf16.h>
#include <math.h>

#define B_   4
#define T_   2048
#define KDIM 1024
#define H_   16
#define D_   64
#define BH_  (B_*H_)      // 64
#define M_   (B_*T_)      // 8192
#define NQT  (T_/64)      // 32

typedef __bf16 bf16;
typedef __bf16 bf16x8 __attribute__((ext_vector_type(8)));
typedef __bf16 bf16x4 __attribute__((ext_vector_type(4)));
typedef float  f32x4  __attribute__((ext_vector_type(4)));

static __device__ __forceinline__ f32x4 mfma16(bf16x8 a, bf16x8 b, f32x4 c) {
    return __builtin_amdgcn_mfma_f32_16x16x32_bf16(a, b, c, 0, 0, 0);
}

// ---------------- fp32 -> bf16 conversion (vectorized) ----------------
__global__ void cvt_f32_to_bf16(const float* __restrict__ src, bf16* __restrict__ dst, int n4) {
    int i = blockIdx.x * blockDim.x + threadIdx.x;
    if (i >= n4) return;
    float4 v = reinterpret_cast<const float4*>(src)[i];
    bf16x4 o;
    o.x = (bf16)v.x; o.y = (bf16)v.y; o.z = (bf16)v.z; o.w = (bf16)v.w;
    reinterpret_cast<bf16x4*>(dst)[i] = o;
}

// ---------------- QKV projection GEMM (NT): C[i][j] = dot(x[i,:], W[j,:]) ----------------
// 128x128 tile, BK=64, 4 waves (2x2), 16x16x32 bf16 MFMA, global_load_lds staging.
// z=0 -> Q (b,h,t,d); z=1 -> K (b,h,t,d); z=2 -> V transposed (b,h,d,t)
__global__ __launch_bounds__(256) void proj_gemm(
    const bf16* __restrict__ xb, const bf16* __restrict__ Wall,
    bf16* __restrict__ Qb, bf16* __restrict__ Kb, bf16* __restrict__ Vtb)
{
    __shared__ __align__(16) bf16 Asm[128*64];
    __shared__ __align__(16) bf16 Bsm[128*64];

    const int tid  = threadIdx.x;
    const int wid  = tid >> 6;
    const int lane = tid & 63;
    const int l15  = lane & 15, l4 = lane >> 4;
    const int wr = wid >> 1, wc = wid & 1;
    const int row0 = blockIdx.x * 128;
    const int col0 = blockIdx.y * 128;
    const int wz   = blockIdx.z;
    const bf16* Wp = Wall + (size_t)wz * KDIM * KDIM;

    f32x4 acc[4][4] = {};

    for (int kt = 0; kt < KDIM/64; ++kt) {
        const int k0 = kt * 64;
        __syncthreads();   // previous compute done reading LDS
#pragma unroll
        for (int i = 0; i < 4; ++i) {
            int chunk = i*256 + tid;            // 16B chunk id, 0..1023
            int rr = chunk >> 3;                // tile row 0..127
            int cc = (chunk & 7) * 8;           // col element 0..56
            const bf16* ga = xb + (size_t)(row0 + rr)*KDIM + k0 + cc;
            bf16* la = Asm + (size_t)(i*256 + wid*64)*8;   // wave-uniform base
            __builtin_amdgcn_global_load_lds(
                (const __attribute__((address_space(1))) void*)ga,
                (__attribute__((address_space(3))) void*)la, 16, 0, 0);
        }
#pragma unroll
        for (int i = 0; i < 4; ++i) {
            int chunk = i*256 + tid;
            int rr = chunk >> 3;
            int cc = (chunk & 7) * 8;
            const bf16* gb = Wp + (size_t)(col0 + rr)*KDIM + k0 + cc;
            bf16* lb = Bsm + (size_t)(i*256 + wid*64)*8;
            __builtin_amdgcn_global_load_lds(
                (const __attribute__((address_space(1))) void*)gb,
                (__attribute__((address_space(3))) void*)lb, 16, 0, 0);
        }
        asm volatile("s_waitcnt vmcnt(0)" ::: "memory");
        __syncthreads();

#pragma unroll
        for (int kk = 0; kk < 2; ++kk) {
            bf16x8 af[4], bfr[4];
#pragma unroll
            for (int m = 0; m < 4; ++m)
                af[m] = *reinterpret_cast<const bf16x8*>(Asm + (wr*64 + m*16 + l15)*64 + kk*32 + l4*8);
#pragma unroll
            for (int n = 0; n < 4; ++n)
                bfr[n] = *reinterpret_cast<const bf16x8*>(Bsm + (wc*64 + n*16 + l15)*64 + kk*32 + l4*8);
#pragma unroll
            for (int m = 0; m < 4; ++m)
#pragma unroll
                for (int n = 0; n < 4; ++n)
                    acc[m][n] = mfma16(af[m], bfr[n], acc[m][n]);
        }
    }

    // epilogue: C/D layout col=lane&15, row=(lane>>4)*4+reg  [m89]
#pragma unroll
    for (int m = 0; m < 4; ++m)
#pragma unroll
        for (int n = 0; n < 4; ++n)
#pragma unroll
            for (int r = 0; r < 4; ++r) {
                int gi = row0 + wr*64 + m*16 + l4*4 + r;   // b*T + t
                int gj = col0 + wc*64 + n*16 + l15;        // h*64 + d
                bf16 o = (bf16)acc[m][n][r];
                int bb = gi >> 11, tt = gi & (T_-1);
                int hh = gj >> 6,  dd = gj & (D_-1);
                size_t bh = (size_t)bb*H_ + hh;
                if (wz == 0)      Qb [(bh*T_ + tt)*D_ + dd] = o;
                else if (wz == 1) Kb [(bh*T_ + tt)*D_ + dd] = o;
                else              Vtb[(bh*D_ + dd)*T_ + tt] = o;
            }
}

// ---------------- causal flash attention ----------------
// block = 256 threads (4 waves); each block: 64 Q-rows of one (b,h); wave w owns rows [w*16, w*16+16)
__global__ __launch_bounds__(256) void flash_attn(
    const bf16* __restrict__ Qb, const bf16* __restrict__ Kb,
    const bf16* __restrict__ Vtb, float* __restrict__ out)
{
    __shared__ uint4 KsmV[512];   // [kv=64][d=64] bf16, XOR-swizzled rows
    __shared__ uint4 VsmV[512];   // [d=64][kv=64] bf16, XOR-swizzled rows
    __shared__ uint4 PsmV[512];   // per-wave [16][64] bf16, XOR-swizzled
    char* Ksm = (char*)KsmV;
    char* Vsm = (char*)VsmV;
    char* Psm = (char*)PsmV;

    const int tid  = threadIdx.x;
    const int wid  = tid >> 6, lane = tid & 63;
    const int l15  = lane & 15, l4 = lane >> 4;
    const int gid  = blockIdx.x;
    const int bh   = gid & (BH_-1);
    const int qt   = NQT - 1 - (gid >> 6);   // heavy tiles launch first
    const int qbase = qt * 64;

    // Q fragments (A-operand): lane holds Q[row=l15][k=(l>>4)*8+j], two K-chunks
    const bf16* qrow = Qb + ((size_t)bh*T_ + qbase + wid*16 + l15)*D_;
    bf16x8 qf0 = *reinterpret_cast<const bf16x8*>(qrow + l4*8);
    bf16x8 qf1 = *reinterpret_cast<const bf16x8*>(qrow + 32 + l4*8);

    f32x4 o[4] = {};
    float mrow[4] = {-INFINITY, -INFINITY, -INFINITY, -INFINITY};
    float lrow[4] = {0.f, 0.f, 0.f, 0.f};
    char* Pw = Psm + wid*2048;

    for (int nt = 0; nt <= qt; ++nt) {
        __syncthreads();   // all waves done with previous K/V tiles
#pragma unroll
        for (int i = 0; i < 2; ++i) {
            int chunk = i*256 + tid;        // 0..511
            int rr = chunk >> 3;            // 0..63
            int cc = (chunk & 7) * 8;
            int sw = (rr & 7) << 4;
            uint4 kv = *reinterpret_cast<const uint4*>(Kb  + ((size_t)bh*T_ + nt*64 + rr)*D_ + cc);
            *reinterpret_cast<uint4*>(Ksm + rr*128 + ((cc*2) ^ sw)) = kv;
            uint4 vv = *reinterpret_cast<const uint4*>(Vtb + ((size_t)bh*D_ + rr)*T_ + nt*64 + cc);
            *reinterpret_cast<uint4*>(Vsm + rr*128 + ((cc*2) ^ sw)) = vv;
        }
        __syncthreads();

        // S = Q K^T  (16 q-rows x 64 kv), 8 MFMA
        f32x4 s[4];
#pragma unroll
        for (int ss = 0; ss < 4; ++ss) {
            int krow = ss*16 + l15;
            int sw = (krow & 7) << 4;
            bf16x8 k0 = *reinterpret_cast<const bf16x8*>(Ksm + krow*128 + ((l4*16) ^ sw));
            bf16x8 k1 = *reinterpret_cast<const bf16x8*>(Ksm + krow*128 + ((64 + l4*16) ^ sw));
            f32x4 z = {};
            z = mfma16(qf0, k0, z);
            z = mfma16(qf1, k1, z);
            s[ss] = z;
        }

        const bool diag = (nt == qt);
        float tmax[4] = {-INFINITY, -INFINITY, -INFINITY, -INFINITY};
#pragma unroll
        for (int ss = 0; ss < 4; ++ss)
#pragma unroll
            for (int r = 0; r < 4; ++r) {
                float v = s[ss][r] * 0.125f;           // (d^-0.25)^2 = 1/sqrt(64)
                if (diag && (ss*16 + l15 > wid*16 + l4*4 + r)) v = -INFINITY;
                s[ss][r] = v;
                tmax[r] = fmaxf(tmax[r], v);
            }
#pragma unroll
        for (int off = 1; off < 16; off <<= 1)
#pragma unroll
            for (int r = 0; r < 4; ++r)
                tmax[r] = fmaxf(tmax[r], __shfl_xor(tmax[r], off));

#pragma unroll
        for (int r = 0; r < 4; ++r) {
            float mnew  = fmaxf(mrow[r], tmax[r]);
            float alpha = __expf(mrow[r] - mnew);      // mrow=-inf on first tile -> 0
            mrow[r] = mnew;
            float psum = 0.f;
#pragma unroll
            for (int ss = 0; ss < 4; ++ss) {
                float p = __expf(s[ss][r] - mnew);     // masked (-inf) -> 0
                s[ss][r] = p;
                psum += p;
            }
            lrow[r] = lrow[r]*alpha + psum;
#pragma unroll
            for (int sd = 0; sd < 4; ++sd) o[sd][r] *= alpha;
            int prow = l4*4 + r;
            int psw  = (prow & 7) << 4;
#pragma unroll
            for (int ss = 0; ss < 4; ++ss) {
                int colb = (ss*16 + l15) * 2;
                *reinterpret_cast<bf16*>(Pw + prow*128 + (colb ^ psw)) = (bf16)s[ss][r];
            }
        }

        // O += P V : A = P (from swizzled LDS), B = V via Vt rows
        {
            int psw = (l15 & 7) << 4;
            bf16x8 pf0 = *reinterpret_cast<const bf16x8*>(Pw + l15*128 + ((l4*16) ^ psw));
            bf16x8 pf1 = *reinterpret_cast<const bf16x8*>(Pw + l15*128 + ((64 + l4*16) ^ psw));
#pragma unroll
            for (int sd = 0; sd < 4; ++sd) {
                int vrow = sd*16 + l15;
                int vsw  = (vrow & 7) << 4;
                bf16x8 v0 = *reinterpret_cast<const bf16x8*>(Vsm + vrow*128 + ((l4*16) ^ vsw));
                bf16x8 v1 = *reinterpret_cast<const bf16x8*>(Vsm + vrow*128 + ((64 + l4*16) ^ vsw));
                o[sd] = mfma16(pf0, v0, o[sd]);
                o[sd] = mfma16(pf1, v1, o[sd]);
            }
        }
    }

    // final row-sum reduce across the 16 lanes sharing each row
#pragma unroll
    for (int off = 1; off < 16; off <<= 1)
#pragma unroll
        for (int r = 0; r < 4; ++r)
            lrow[r] += __shfl_xor(lrow[r], off);

    const int bb = bh >> 4, hh = bh & 15;
#pragma unroll
    for (int sd = 0; sd < 4; ++sd)
#pragma unroll
        for (int r = 0; r < 4; ++r) {
            int t    = qbase + wid*16 + l4*4 + r;
            int feat = hh*64 + sd*16 + l15;
            out[((size_t)bb*T_ + t)*KDIM + feat] = o[sd][r] / lrow[r];
        }
}

// ---------------- host launch ----------------
extern "C" void kernel_launch(void* const* d_in, const int* in_sizes, int n_in,
                              void* d_out, int out_size, void* d_ws, size_t ws_size,
                              hipStream_t stream) {
    (void)in_sizes; (void)n_in; (void)out_size; (void)ws_size;
    const float* x  = (const float*)d_in[0];
    const float* Wq = (const float*)d_in[1];
    const float* Wk = (const float*)d_in[2];
    const float* Wv = (const float*)d_in[3];
    float* out = (float*)d_out;

    bf16* xb  = (bf16*)d_ws;                       // 8388608 elems
    bf16* Wb  = xb + (size_t)M_*KDIM;              // 3 x 1048576
    bf16* Qb  = Wb + (size_t)3*KDIM*KDIM;          // 8388608 (b,h,t,d)
    bf16* Kb  = Qb + (size_t)M_*KDIM;              // 8388608 (b,h,t,d)
    bf16* Vtb = Kb + (size_t)M_*KDIM;              // 8388608 (b,h,d,t)

    const int n4x = M_*KDIM/4;
    const int n4w = KDIM*KDIM/4;
    cvt_f32_to_bf16<<<(n4x+255)/256, 256, 0, stream>>>(x,  xb, n4x);
    cvt_f32_to_bf16<<<(n4w+255)/256, 256, 0, stream>>>(Wq, Wb,               n4w);
    cvt_f32_to_bf16<<<(n4w+255)/256, 256, 0, stream>>>(Wk, Wb + (size_t)KDIM*KDIM,   n4w);
    cvt_f32_to_bf16<<<(n4w+255)/256, 256, 0, stream>>>(Wv, Wb + (size_t)2*KDIM*KDIM, n4w);

    proj_gemm<<<dim3(M_/128, KDIM/128, 3), 256, 0, stream>>>(xb, Wb, Qb, Kb, Vtb);
    flash_attn<<<dim3(BH_*NQT), 256, 0, stream>>>(Qb, Kb, Vtb, out);
}